// Round 23
// baseline (166.691 us; speedup 1.0000x reference)
//
#include <hip/hip_runtime.h>
#include <hip/hip_bf16.h>

// ---------------------------------------------------------------------------
// SCSAttention on MI355X, round 23 = round 22 with the gmm4 grid-sizing bug
// fixed: bzf encodes batch*split-K, so ga1 needs 32 blocks (2z x 16) and gd
// needs 64 (2z x 2my x 16) -- r22 halved them, never computing the Y branches.
// Grid 408 = 8x51 (bijective XCD swizzle). 128x128 tile, 7 launches, f16.
// ---------------------------------------------------------------------------

typedef __attribute__((ext_vector_type(8))) _Float16 half8;
typedef __attribute__((ext_vector_type(4))) float f32x4;

#define TOKENS 1568

__device__ __forceinline__ ushort f2h(float f) {
    _Float16 h = (_Float16)f;            // RNE
    return *(ushort*)&h;
}
__device__ __forceinline__ float h2f(ushort u) {
    _Float16 h = *(_Float16*)&u;
    return (float)h;
}

__device__ __forceinline__ void gl16(const void* g, void* l) {
    __builtin_amdgcn_global_load_lds(
        (const __attribute__((address_space(1))) unsigned int*)g,
        (__attribute__((address_space(3))) unsigned int*)l, 16, 0, 0);
}

#define EPI_PART  0
#define EPI_F16   1
#define EPI_QK2   2
#define EPI_FINAL 3

struct GA {
    const ushort* Ah; int lda; long sA;
    const ushort* Wh; int ldw; long sW;
    const float* bias; int sB;
    int nkc, Kc;
    float* fO; ushort* bO; ushort* bO2;
    int ldc; long sC; int M, N;
    int nx, ny;
    const float *ex, *gamma; float* fout;
};

// Tile 128(M)x128(N), BK=32, 4 waves (2x2), wave = 64x64 = 4x4 16x16 frags.
// Double-buffered global_load_lds staging; staging in 2 rounds per operand.
template<int EPI>
__device__ __forceinline__ void gmm_body(const GA g, int bx, int by, int bzf,
                                         ushort* LA, ushort* LW)
{
    const int tid = threadIdx.x;
    const int bz = bzf / g.nkc;
    const int kc = bzf % g.nkc;
    const int row0 = by * 128, col0 = bx * 128;

    const int srow = tid >> 2;                     // 0..63
    const int sq   = (tid & 3) ^ (srow & 3);       // XOR k-chunk swizzle
    const long kbase = (long)kc * g.Kc + sq * 8;
    int am0 = row0 + srow;       if (am0 > g.M - 1) am0 = g.M - 1;
    int am1 = row0 + 64 + srow;  if (am1 > g.M - 1) am1 = g.M - 1;
    int wn0 = col0 + srow;       if (wn0 > g.N - 1) wn0 = g.N - 1;
    int wn1 = col0 + 64 + srow;  if (wn1 > g.N - 1) wn1 = g.N - 1;
    const ushort* gA0 = g.Ah + bz * g.sA + (long)am0 * g.lda + kbase;
    const ushort* gA1 = g.Ah + bz * g.sA + (long)am1 * g.lda + kbase;
    const ushort* gW0 = g.Wh + bz * g.sW + (long)wn0 * g.ldw + kbase;
    const ushort* gW1 = g.Wh + bz * g.sW + (long)wn1 * g.ldw + kbase;
    const int wb = (tid & 192) * 8;                // wave-uniform LDS base

    auto STAGE = [&](int buf, int k0) {
        gl16(gA0 + k0, LA + buf * 4096 + wb);
        gl16(gA1 + k0, LA + buf * 4096 + 2048 + wb);
        gl16(gW0 + k0, LW + buf * 4096 + wb);
        gl16(gW1 + k0, LW + buf * 4096 + 2048 + wb);
    };

    const int lane = tid & 63, wv = tid >> 6;
    const int wr = (wv >> 1) * 64, wc = (wv & 1) * 64;
    const int fr = lane & 15;
    const int ksw = ((lane >> 4) ^ (lane & 3)) * 8;
    int aoff[4], boff[4];
#pragma unroll
    for (int mi = 0; mi < 4; ++mi) aoff[mi] = (wr + mi * 16 + fr) * 32 + ksw;
#pragma unroll
    for (int ni = 0; ni < 4; ++ni) boff[ni] = (wc + ni * 16 + fr) * 32 + ksw;

    f32x4 acc[4][4];
#pragma unroll
    for (int mi = 0; mi < 4; ++mi)
#pragma unroll
        for (int ni = 0; ni < 4; ++ni) acc[mi][ni] = (f32x4){0.f, 0.f, 0.f, 0.f};

    STAGE(0, 0);
    __syncthreads();
    int cur = 0;
    for (int k0 = 0; k0 < g.Kc; k0 += 32) {
        if (k0 + 32 < g.Kc) STAGE(cur ^ 1, k0 + 32);   // prefetch next K-tile

        half8 fa[4], fb[4];
#pragma unroll
        for (int mi = 0; mi < 4; ++mi) fa[mi] = *(half8*)&LA[cur * 4096 + aoff[mi]];
#pragma unroll
        for (int ni = 0; ni < 4; ++ni) fb[ni] = *(half8*)&LW[cur * 4096 + boff[ni]];
#pragma unroll
        for (int mi = 0; mi < 4; ++mi)
#pragma unroll
            for (int ni = 0; ni < 4; ++ni)
                acc[mi][ni] = __builtin_amdgcn_mfma_f32_16x16x32_f16(fa[mi], fb[ni], acc[mi][ni], 0, 0, 0);
        __syncthreads();
        cur ^= 1;
    }

    const int q4 = (lane >> 4) * 4;
    float gg = 0.f;
    if constexpr (EPI == EPI_FINAL) gg = g.gamma[0];
#pragma unroll
    for (int mi = 0; mi < 4; ++mi)
#pragma unroll
        for (int ni = 0; ni < 4; ++ni)
#pragma unroll
            for (int qi = 0; qi < 4; ++qi) {
                int m = row0 + wr + mi * 16 + q4 + qi;
                int n = col0 + wc + ni * 16 + fr;
                if (m >= g.M || n >= g.N) continue;
                float v = acc[mi][ni][qi];
                if (g.bias) v += g.bias[bz * g.sB + n];
                if constexpr (EPI == EPI_PART) {
                    g.fO[(long)bzf * g.sC + (long)m * g.ldc + n] = v;
                } else if constexpr (EPI == EPI_F16) {
                    g.bO[(long)bzf * g.sC + (long)m * g.ldc + n] = f2h(v);
                } else if constexpr (EPI == EPI_QK2) {
                    // n<128: K channel 128+n scatter into Km ; n>=128: Q col n
                    ushort h = f2h(v);
                    if (n < 128) {
                        int c = 128 + n;
                        int p = m % 49, img = m / 49, f = img & 7, b = img >> 3;
                        int flat = (p / 7) * 14336 + f * 1792 + (p % 7) * 256 + c;
                        int ci = flat / 392, mm = flat % 392;
                        g.bO2[(long)b * 100352 + (long)mm * 256 + ci] = h;
                    } else {
                        g.bO[m * 256 + n] = h;
                    }
                } else {
                    int nimg = m / 49, p = m % 49;
                    long xi = (long)nimg * (2048 * 49) + (long)n * 49 + p;
                    float xv = g.ex[xi];
                    g.fout[xi] = (gg * v + xv) * v + xv;
                }
            }
}

template<int EPI>
__global__ __launch_bounds__(256)
void gmm(GA g)
{
    __shared__ __align__(16) ushort LA[2 * 4096], LW[2 * 4096];
    gmm_body<EPI>(g, blockIdx.x, blockIdx.y, blockIdx.z, LA, LW);
}

// Flat-grid final GEMM with XCD swizzle: 208 blocks = 8 x 26 (bijective).
__global__ __launch_bounds__(256)
void gmmF(GA g)
{
    __shared__ __align__(16) ushort LA[2 * 4096], LW[2 * 4096];
    int id = blockIdx.x;
    id = (id & 7) * 26 + (id >> 3);                // XCD-chunked remap
    gmm_body<EPI_FINAL>(g, id % g.nx, id / g.nx, 0, LA, LW);
}

// Flat-grid quad GEMM with XCD swizzle: [0,n1) g1 ; [n1,+n2) g2 ; [..,+n3) g3 ;
// rest g4. Grid must be 408 = 8 x 51 (bijective remap).
__global__ __launch_bounds__(256)
void gmm4(GA g1, int n1, GA g2, int n2, GA g3, int n3, GA g4)
{
    __shared__ __align__(16) ushort LA[2 * 4096], LW[2 * 4096];
    int id = blockIdx.x;
    id = (id & 7) * 51 + (id >> 3);                // XCD-chunked remap
    if (id < n1) {
        int bx = id % g1.nx, t = id / g1.nx;
        gmm_body<EPI_PART>(g1, bx, t % g1.ny, t / g1.ny, LA, LW);
    } else if (id < n1 + n2) {
        id -= n1;
        int bx = id % g2.nx, t = id / g2.nx;
        gmm_body<EPI_PART>(g2, bx, t % g2.ny, t / g2.ny, LA, LW);
    } else if (id < n1 + n2 + n3) {
        id -= n1 + n2;
        int bx = id % g3.nx, t = id / g3.nx;
        gmm_body<EPI_PART>(g3, bx, t % g3.ny, t / g3.ny, LA, LW);
    } else {
        id -= n1 + n2 + n3;
        int bx = id % g4.nx, t = id / g4.nx;
        gmm_body<EPI_PART>(g4, bx, t % g4.ny, t / g4.ny, LA, LW);
    }
}

// prep: [0,12290) weight conversions ; [12290,14338) activation transposes ;
// [14338,14722) weight transposes (w2u, w2uY, wv). All f16 single plane.
__global__ __launch_bounds__(256)
void prep(const float* c11, const float* c21, const float* conv3,
          const float* c22, const float* c12, const float* wval,
          const float* w2dX, const float* w2dY,
          const float* b_c11, const float* b_c21, const float* b_conv3,
          const float* x, const float* dX,
          const float* w2u, const float* w2uY, const float* wv,
          ushort* Wg1, ushort* C2, ushort* Wval, ushort* W2dS, float* bg1,
          ushort* Xt, ushort* DXt,
          ushort* W2uT, ushort* WvT)
{
    __shared__ float tile[64][65];
    int b = blockIdx.x;
    int tid = threadIdx.x;
    if (b < 12290) {
        int e = b * 256 + tid;
        if (e < 1048576) {
            float v = e < 262144 ? c11[e] : e < 524288 ? c21[e - 262144] : conv3[e - 524288];
            Wg1[e] = f2h(v);
        } else if (e < 1572864) {
            int i = e - 1048576;
            C2[i] = f2h(i < 262144 ? c22[i] : c12[i - 262144]);
        } else if (e < 2097152) {
            int i = e - 1572864; Wval[i] = f2h(wval[i]);
        } else if (e < 2097664) {
            int i = e - 2097152;
            bg1[i] = i < 128 ? b_c11[i] : i < 256 ? b_c21[i - 128] : b_conv3[i - 256];
        } else {
            int i = e - 2097664;                   // < 1048576
            W2dS[i] = f2h(i < 524288 ? w2dX[i] : w2dY[i - 524288]);
        }
    } else if (b < 14338) {
        int local = b - 12290;                 // 0..2047
        int z = local >> 10;
        int rem = local & 1023;
        int n = rem & 31, c0 = (rem >> 5) * 64;
        const float* src = z ? dX : x;
        ushort* oh = z ? DXt : Xt;
        const float* s = src + (long)n * (2048 * 49) + (long)c0 * 49;
        for (int idx = tid; idx < 64 * 49; idx += 256)
            tile[idx / 49][idx % 49] = s[idx];
        __syncthreads();
        for (int idx = tid; idx < 49 * 64; idx += 256) {
            int p = idx >> 6, cl = idx & 63;
            long o = (long)(n * 49 + p) * 2048 + c0 + cl;
            oh[o] = f2h(tile[cl][p]);
        }
    } else {
        int local = b - 14338;                // 0..383
        int zc = local >> 7, t = local & 127;
        const float* src; ushort* dh;
        switch (zc) {
            case 0:  src = w2u;  dh = W2uT;          break;
            case 1:  src = w2uY; dh = W2uT + 524288; break;
            default: src = wv;   dh = WvT;           break;
        }
        const int rows = 2048, cols = 256;
        int tilesX = cols >> 6;               // 4
        int tx = t % tilesX, ty = t / tilesX;
        for (int i = tid; i < 4096; i += 256) {
            int r = i >> 6, c = i & 63;
            tile[r][c] = src[(long)(ty * 64 + r) * cols + tx * 64 + c];
        }
        __syncthreads();
        for (int i = tid; i < 4096; i += 256) {
            int c = i >> 6, r = i & 63;
            long o = (long)(tx * 64 + c) * rows + ty * 64 + r;
            dh[o] = f2h(tile[r][c]);
        }
    }
}

// Fused reduces: [0,3136) r_g1 (4 chunks) ; [3136,3200) A1 reduce ;
// [3200,3232) D reduce -> DT ; [3232,3360) dvec ; [3360,4928) P0 reduce (4 chunks).
__global__ __launch_bounds__(256)
void redA(const float* __restrict__ PG1, const float* __restrict__ bg1,
          const float* __restrict__ pos,
          ushort* Q, ushort* Km, ushort* V,
          const float* __restrict__ A1p, ushort* A1,
          const float* __restrict__ Dp, ushort* DT,
          const float* __restrict__ P0p, ushort* P0,
          const float* w2dX, const float* w2dY,
          const float* b1dX, const float* b1uX, const float* b2dX,
          const float* b1dY, const float* b1uY, const float* b2dY,
          float* __restrict__ dvec)
{
    int blk = blockIdx.x, tid = threadIdx.x;
    if (blk < 3136) {
        int idx = blk * 256 + tid;                 // 1568*512
        int m = idx >> 9, n = idx & 511;
        float v = bg1[n];
#pragma unroll
        for (int k = 0; k < 4; ++k) v += PG1[(long)k * 802816 + idx];
        int p = m % 49, img = m / 49;
        int f = img & 7, b = img >> 3;
        if (n < 128) {
            Q[m * 256 + n] = f2h(v);
        } else if (n < 256) {
            int c = n - 128;
            int flat = (p / 7) * 14336 + f * 1792 + (p % 7) * 256 + c;
            int ci = flat / 392, mm = flat % 392;
            Km[(long)b * 100352 + (long)mm * 256 + ci] = f2h(v);
        } else {
            int c = n - 256;
            v += pos[f * 12544 + c * 49 + p];
            int s = m % 392;
            long o = (long)b * 106496 + (long)c * 416 + s;
            V[o] = f2h(v);
            if (s < 24) V[o + 392] = 0;            // zero K-pad columns
        }
    } else if (blk < 3200) {
        int b2 = blk - 3136;                       // 0..63
#pragma unroll
        for (int r = 0; r < 4; ++r) {
            int idx = b2 * 1024 + r * 256 + tid;   // < 65536
            int z = idx >> 15, e = idx & 32767;
            float v = 0.f;
#pragma unroll
            for (int k = 0; k < 8; ++k) v += A1p[(long)(z * 8 + k) * 32768 + e];
            A1[idx] = f2h(v);
        }
    } else if (blk < 3232) {
        int b2 = blk - 3200;                       // 0..31
#pragma unroll
        for (int r = 0; r < 16; ++r) {
            int idx = b2 * 4096 + r * 256 + tid;   // < 131072
            int z = idx >> 16, e = idx & 65535;
            int i = e >> 8, j = e & 255;
            float v = 0.f;
#pragma unroll
            for (int k = 0; k < 8; ++k) v += Dp[(long)(z * 8 + k) * 65536 + e];
            DT[(long)z * 65536 + (long)j * 256 + i] = f2h(v);   // DT = D^T
        }
    } else if (blk < 3360) {
        int blk2 = blk - 3232;                     // 0..127
        int z = blk2 >> 6;
        int lane = tid & 63, wv = tid >> 6;
        int c = (blk2 & 63) * 4 + wv;
        const float* w2d = (z ? w2dY : w2dX) + (long)c * 2048;
        const float* b1d = z ? b1dY : b1dX;
        const float* b1u = z ? b1uY : b1uX;
        const float* b2d = z ? b2dY : b2dX;
        float acc = 0.f;
        for (int o = lane; o < 2048; o += 64) acc = fmaf(w2d[o], b1u[o], acc);
        for (int j = lane; j < 256; j += 64) {
            float d = 0.f;
#pragma unroll
            for (int k = 0; k < 8; ++k) d += Dp[(long)(z * 8 + k) * 65536 + (long)c * 256 + j];
            acc = fmaf(d, b1d[j], acc);
        }
        for (int off = 32; off; off >>= 1) acc += __shfl_down(acc, off, 64);
        if (lane == 0) dvec[z * 256 + c] = acc + b2d[c];
    } else {
        int idx = (blk - 3360) * 256 + tid;        // < 401408
        float v = 0.f;
#pragma unroll
        for (int k = 0; k < 4; ++k) v += P0p[(long)k * 401408 + idx];
        P0[idx] = f2h(v);
    }
}

// A3+kc launch: [0,4) gmm (A3 = A1 @ DT^T, f16, 128-tile) ; [4,68) kc:
//   kc_z[i] = A1_z[i]·dvec_z + C2_z[i]·b2u_z + bc_z[i]
__global__ __launch_bounds__(256)
void a3kc(GA gA3,
          const ushort* __restrict__ A1, const float* __restrict__ dvec,
          const float* c22, const float* c12,
          const float* b2uX, const float* b2uY,
          const float* bc22, const float* bc12, float* kc)
{
    __shared__ __align__(16) ushort LA[2 * 4096], LW[2 * 4096];
    int id = blockIdx.x;
    if (id < 4) {
        gmm_body<EPI_F16>(gA3, id & 1, 0, id >> 1, LA, LW);
        return;
    }
    int tid = threadIdx.x, lane = tid & 63, wv = tid >> 6;
    int w = (id - 4) * 4 + wv;                     // 0..255
    int z = w >> 7, i = w & 127;
    const ushort* a1 = A1 + (long)z * 32768 + i * 256;
    const float* dv = dvec + z * 256;
    const float* cr = (z ? c12 : c22) + (long)i * 2048;
    const float* b2u = z ? b2uY : b2uX;
    float acc = 0.f;
    for (int c = lane; c < 256; c += 64) acc = fmaf(h2f(a1[c]), dv[c], acc);
    for (int o = lane; o < 2048; o += 64) acc = fmaf(cr[o], b2u[o], acc);
    for (int off = 32; off; off >>= 1) acc += __shfl_down(acc, off, 64);
    if (lane == 0) kc[z * 128 + i] = acc + (z ? bc12 : bc22)[i];
}

// Fused attention, 512 threads / 8 waves: waves split the 26 col-frags by 8
// (phase 1) and the 16 PV channel-frags by 2 (phase 3). Softmax (phase 2)
// runs on threads 0..255. Block = 16 Q-rows x one batch, grid 25x4.
__global__ __launch_bounds__(512)
void fattn(const ushort* __restrict__ Qg, const ushort* __restrict__ Kmg,
           const ushort* __restrict__ VT, ushort* __restrict__ O)
{
    __shared__ float raw[16 * 420];
    __shared__ ushort P[16 * 424];
    const int b = blockIdx.y;
    const int r0 = blockIdx.x * 16;
    const int tid = threadIdx.x;
    const int lane = tid & 63, wv = tid >> 6;      // 8 waves
    const int fr = lane & 15, g = lane >> 4;
    const int kb = g * 8;
    const long base = (long)b * 100352;
    const long vbase = (long)b * 106496;

    int qr = r0 + fr; if (qr > 391) qr = 391;
    const ushort* qp = Qg + base + (long)qr * 256 + kb;
    half8 qh[8];
#pragma unroll
    for (int kf = 0; kf < 8; ++kf) qh[kf] = *(const half8*)(qp + kf * 32);

    // Phase 1: wave wv handles nf = wv, wv+8, ... (26 col-frags of 16)
    for (int nf = wv; nf < 26; nf += 8) {
        int kcol = nf * 16 + fr; if (kcol > 391) kcol = 391;
        const ushort* kp = Kmg + base + (long)kcol * 256 + kb;
        f32x4 a = (f32x4){0.f, 0.f, 0.f, 0.f};
#pragma unroll
        for (int kf = 0; kf < 8; ++kf) {
            half8 bh = *(const half8*)(kp + kf * 32);
            a = __builtin_amdgcn_mfma_f32_16x16x32_f16(qh[kf], bh, a, 0, 0, 0);
        }
#pragma unroll
        for (int q = 0; q < 4; ++q)
            raw[(g * 4 + q) * 420 + nf * 16 + fr] = a[q];
    }
    __syncthreads();

    // Phase 2: softmax on threads 0..255 (row = tid>>4, j = tid&15)
    if (tid < 256) {
        int row = tid >> 4, j = tid & 15;
        float v[26];
        float m = -1e30f;
#pragma unroll
        for (int k = 0; k < 26; ++k) {
            int col = j + 16 * k;
            v[k] = (col < 392) ? raw[row * 420 + col] : -1e30f;
            m = fmaxf(m, v[k]);
        }
#pragma unroll
        for (int off = 8; off; off >>= 1) m = fmaxf(m, __shfl_xor(m, off, 16));
        float s = 0.f;
#pragma unroll
        for (int k = 0; k < 26; ++k) { v[k] = __expf(v[k] - m); s += v[k]; }
#pragma unroll
        for (int off = 8; off; off >>= 1) s += __shfl_xor(s, off, 16);
        float inv = 1.f / s;
#pragma unroll
        for (int k = 0; k < 26; ++k) {
            int col = j + 16 * k;
            P[row * 424 + col] = (col < 392) ? f2h(v[k] * inv) : (ushort)0;
        }
    }
    __syncthreads();

    // Phase 3: PV. wave wv computes output channel frags wv*2, wv*2+1.
    const int cf0 = wv * 2;
    f32x4 o[2];
#pragma unroll
    for (int c = 0; c < 2; ++c) o[c] = (f32x4){0.f, 0.f, 0.f, 0.f};
#pragma unroll
    for (int kf = 0; kf < 13; ++kf) {
        half8 pa = *(half8*)&P[fr * 424 + kf * 32 + kb];
#pragma unroll
        for (int c = 0; c < 2; ++c) {
            const ushort* vp = VT + vbase + (long)((cf0 + c) * 16 + fr) * 416 + kf * 32 + kb;
            half8 vb = *(const half8*)vp;
            o[c] = __builtin_amdgcn_mfma_f32_16x16x32_f16(pa, vb, o[c], 0, 0, 0);
        }
    }
#pragma unroll
    for (int c = 0; c < 2; ++c)
#pragma unroll
        for (int q = 0; q < 4; ++q) {
            int orow = r0 + g * 4 + q;
            if (orow < 392)
                O[base + (long)orow * 256 + (cf0 + c) * 16 + fr] = f2h(o[c][q]);
        }
}

extern "C" void kernel_launch(void* const* d_in, const int* in_sizes, int n_in,
                              void* d_out, int out_size, void* d_ws, size_t ws_size,
                              hipStream_t stream)
{
    const float* x        = (const float*)d_in[0];
    const float* domainX  = (const float*)d_in[1];
    const float* w_conv3  = (const float*)d_in[5];
    const float* b_conv3  = (const float*)d_in[6];
    const float* w_value  = (const float*)d_in[7];
    const float* b_value  = (const float*)d_in[8];
    const float* b_l1down   = (const float*)d_in[9];
    const float* b_l1up     = (const float*)d_in[10];
    const float* b_l1down_Y = (const float*)d_in[11];
    const float* b_l1up_Y   = (const float*)d_in[12];
    const float* w_l2down   = (const float*)d_in[13];
    const float* b_l2down   = (const float*)d_in[14];
    const float* w_l2up     = (const float*)d_in[15];
    const float* b_l2up     = (const float*)d_in[16];
    const float* w_l2down_Y = (const float*)d_in[17];
    const float* b_l2down_Y = (const float*)d_in[18];
    const float* w_l2up_Y   = (const float*)d_in[19];
    const float* b_l2up_Y   = (const float*)d_in[20];
    const float* w_c11 = (const float*)d_in[21];
    const float* b_c11 = (const float*)d_in[22];
    const float* w_c12 = (const float*)d_in[23];
    const float* b_c12 = (const float*)d_in[24];
    const float* w_c21 = (const float*)d_in[25];
    const float* b_c21 = (const float*)d_in[26];
    const float* w_c22 = (const float*)d_in[27];
    const float* b_c22 = (const float*)d_in[28];
    const float* pos   = (const float*)d_in[29];
    const float* gamma = (const float*)d_in[30];
    float* out = (float*)d_out;

    ushort* U = (ushort*)d_ws;
    float*  Fp = (float*)d_ws;

    // ---- flat workspace (ushort elems; f32 region after) ----
    const long oXt   = 0;            // [1568][2048]
    const long oDXt  = 3211264;
    const long oWg1  = 6422528;      // [512][2048] c11|c21|conv3
    const long oWval = 7471104;      // [2048][256]
    const long oC2   = 7995392;      // [2][128][2048]
    const long oW2uT = 8519680;      // [2][256][2048]
    const long oWvT  = 9568256;      // [256][2048]
    const long oW2dS = 10092544;     // [2][256][2048]
    const long oQ    = 11141120;     // [1568][256]
    const long oKm   = 11542528;     // [4][392][256]
    const long oVT   = 11943936;     // [4][256][416]
    const long oA1   = 12369920;     // [2][128][256]
    const long oDT   = 12435456;     // [2][256][256]
    const long oA3   = 12566528;     // [2][128][256] = flat [256][256]
    const long oP0   = 12632064;     // [1568][256]
    const long oO    = 13033472;     // [1568][256], ends 13,434,880
    // float offsets (float elems)
    const long fPG1  = 6979584;      // [4][1568][512]
    const long fP0p  = 13402112;     // [4][1568][256]
    const long fA1p  = 15007744;     // [16][128][256]
    const long fDp   = 15532032;     // [16][256][256]
    const long fbg1  = 16580608;     // 512
    const long fkc   = 16581120;     // 256
    const long fdv   = 16581376;     // 512

    GA Z = {};

    // 1. prep
    prep<<<dim3(14722), 256, 0, stream>>>(
        w_c11, w_c21, w_conv3, w_c22, w_c12, w_value, w_l2down, w_l2down_Y,
        b_c11, b_c21, b_conv3, x, domainX,
        w_l2up, w_l2up_Y, w_value,
        U + oWg1, U + oC2, U + oWval, U + oW2dS, Fp + fbg1,
        U + oXt, U + oDXt,
        U + oW2uT, U + oWvT);

    // 2. G1 (208, split-K 4) + A1 partials (32) + D partials (64) + P0 partials (104)
    {
        GA g1 = Z;
        g1.Ah = U + oXt; g1.lda = 2048; g1.sA = 0;
        g1.Wh = U + oWg1; g1.ldw = 2048; g1.sW = 0;
        g1.nkc = 4; g1.Kc = 512; g1.fO = Fp + fPG1;
        g1.ldc = 512; g1.sC = 802816; g1.M = TOKENS; g1.N = 512; g1.nx = 4; g1.ny = 13;
        GA ga1 = Z;
        ga1.Ah = U + oC2; ga1.lda = 2048; ga1.sA = 262144;
        ga1.Wh = U + oW2uT; ga1.ldw = 2048; ga1.sW = 524288;
        ga1.nkc = 8; ga1.Kc = 256; ga1.fO = Fp + fA1p;
        ga1.ldc = 256; ga1.sC = 32768; ga1.M = 128; ga1.N = 256; ga1.nx = 2; ga1.ny = 1;
        GA gd = Z;
        gd.Ah = U + oW2dS; gd.lda = 2048; gd.sA = 524288;
        gd.Wh = U + oWvT; gd.ldw = 2048; gd.sW = 0;
        gd.nkc = 8; gd.Kc = 256; gd.fO = Fp + fDp;
        gd.ldc = 256; gd.sC = 65536; gd.M = 256; gd.N = 256; gd.nx = 2; gd.ny = 2;
        GA gp = Z;
        gp.Ah = U + oDXt; gp.lda = 2048; gp.sA = 0;
        gp.Wh = U + oWg1 + 524288; gp.ldw = 2048; gp.sW = 0;   // conv3 rows
        gp.nkc = 4; gp.Kc = 512; gp.fO = Fp + fP0p;
        gp.ldc = 256; gp.sC = 401408; gp.M = TOKENS; gp.N = 256; gp.nx = 2; gp.ny = 13;
        gmm4<<<dim3(408), 256, 0, stream>>>(g1, 208, ga1, 32, gd, 64, gp);
    }

    // 3. r_g1 (4 chunks) + A1 reduce + D reduce->DT + dvec + P0 reduce
    redA<<<dim3(4928), 256, 0, stream>>>(Fp + fPG1, Fp + fbg1, pos,
        U + oQ, U + oKm, U + oVT,
        Fp + fA1p, U + oA1,
        Fp + fDp, U + oDT,
        Fp + fP0p, U + oP0,
        w_l2down, w_l2down_Y,
        b_l1down, b_l1up, b_l2down,
        b_l1down_Y, b_l1up_Y, b_l2down_Y,
        Fp + fdv);

    // 4. A3 = A1 @ DT^T (4 blocks, f16, 128-tile) + kc (64 wave-parallel blocks)
    {
        GA g = Z;
        g.Ah = U + oA1; g.lda = 256; g.sA = 32768;
        g.Wh = U + oDT; g.ldw = 256; g.sW = 65536;
        g.nkc = 1; g.Kc = 256; g.bO = U + oA3;
        g.ldc = 256; g.sC = 32768; g.M = 128; g.N = 256; g.nx = 2; g.ny = 1;
        a3kc<<<dim3(68), 256, 0, stream>>>(g,
            U + oA1, Fp + fdv,
            w_c22, w_c12, b_l2up, b_l2up_Y,
            b_c22, b_c12, Fp + fkc);
    }

    // 5. GQK2 = P0 @ A3^T + kc, fused Q/Km scatter epilogue (K=256, 26 blocks)
    {
        GA g = Z;
        g.Ah = U + oP0; g.lda = 256; g.sA = 0;
        g.Wh = U + oA3; g.ldw = 256; g.sW = 0;
        g.bias = Fp + fkc; g.sB = 0;
        g.nkc = 1; g.Kc = 256;
        g.bO = U + oQ; g.bO2 = U + oKm;
        g.ldc = 0; g.sC = 0; g.M = TOKENS; g.N = 256; g.nx = 2; g.ny = 13;
        gmm<EPI_QK2><<<dim3(2, 13, 1), 256, 0, stream>>>(g);
    }

    // 6. fused attention (100 blocks x 8 waves)
    fattn<<<dim3(25, 4), 512, 0, stream>>>(U + oQ, U + oKm, U + oVT, U + oO);

    // 7. final: z = O @ w_value^T + b_value ; out = (g*z + x)*z + x  (XCD swizzle)
    {
        GA g = Z;
        g.Ah = U + oO; g.lda = 256; g.sA = 0;
        g.Wh = U + oWval; g.ldw = 256; g.sW = 0;
        g.bias = b_value; g.sB = 0;
        g.nkc = 1; g.Kc = 256;
        g.ldc = 0; g.sC = 0; g.M = TOKENS; g.N = 2048; g.nx = 16; g.ny = 13;
        g.ex = x; g.gamma = gamma; g.fout = out;
        gmmF<<<dim3(208), 256, 0, stream>>>(g);
    }
}

// Round 24
// 139.305 us; speedup vs baseline: 1.1966x; 1.1966x over previous
//
#include <hip/hip_runtime.h>
#include <hip/hip_bf16.h>

// ---------------------------------------------------------------------------
// SCSAttention on MI355X, round 24 = round 21/19 verbatim (best known-good,
// 139.8-141.0us, fully validated incl. post-timing revalidation).
// Round 23's 128x128 tile reverted: VGPR allocator capped at 72 -> 64-reg
// accumulator spilled to scratch (gmmF 39us, MfmaUtil 1.45%, 213K bank conf).
// 7 launches, all f16 single-pass, 2-buffer LDS-staged 64x128 GEMMs,
// XCD-aware block swizzles, algebraically collapsed domain chain.
// ---------------------------------------------------------------------------

typedef __attribute__((ext_vector_type(8))) _Float16 half8;
typedef __attribute__((ext_vector_type(4))) float f32x4;

#define TOKENS 1568

__device__ __forceinline__ ushort f2h(float f) {
    _Float16 h = (_Float16)f;            // RNE
    return *(ushort*)&h;
}
__device__ __forceinline__ float h2f(ushort u) {
    _Float16 h = *(_Float16*)&u;
    return (float)h;
}

__device__ __forceinline__ void gl16(const void* g, void* l) {
    __builtin_amdgcn_global_load_lds(
        (const __attribute__((address_space(1))) unsigned int*)g,
        (__attribute__((address_space(3))) unsigned int*)l, 16, 0, 0);
}

#define EPI_PART  0
#define EPI_F16   1
#define EPI_QK2   2
#define EPI_FINAL 3

struct GA {
    const ushort* Ah; int lda; long sA;
    const ushort* Wh; int ldw; long sW;
    const float* bias; int sB;
    int nkc, Kc;
    float* fO; ushort* bO; ushort* bO2;
    int ldc; long sC; int M, N;
    int nx, ny;
    const float *ex, *gamma; float* fout;
};

// Tile 64(M)x128(N), BK=32, 4 waves (2x2), wave = 32x64 = 2x4 16x16 frags.
// Double-buffered global_load_lds staging (round-14 proven form).
template<int EPI>
__device__ __forceinline__ void gmm_body(const GA g, int bx, int by, int bzf,
                                         ushort* LA, ushort* LW)
{
    const int tid = threadIdx.x;
    const int bz = bzf / g.nkc;
    const int kc = bzf % g.nkc;
    const int row0 = by * 64, col0 = bx * 128;

    const int srow = tid >> 2;
    const int sq   = (tid & 3) ^ (srow & 3);
    int am  = row0 + srow;      if (am  > g.M - 1) am  = g.M - 1;
    int wn0 = col0 + srow;      if (wn0 > g.N - 1) wn0 = g.N - 1;
    int wn1 = col0 + 64 + srow; if (wn1 > g.N - 1) wn1 = g.N - 1;
    const long kbase = (long)kc * g.Kc + sq * 8;
    const ushort* gA  = g.Ah + bz * g.sA + (long)am  * g.lda + kbase;
    const ushort* gW0 = g.Wh + bz * g.sW + (long)wn0 * g.ldw + kbase;
    const ushort* gW1 = g.Wh + bz * g.sW + (long)wn1 * g.ldw + kbase;
    const int wb = (tid & 192) * 8;

    auto STAGE = [&](int buf, int k0) {
        gl16(gA + k0, LA + buf * 2048 + wb);
        gl16(gW0 + k0, LW + buf * 4096 + wb);
        gl16(gW1 + k0, LW + buf * 4096 + 2048 + wb);
    };

    const int lane = tid & 63, wv = tid >> 6;
    const int wr = (wv >> 1) * 32, wc = (wv & 1) * 64;
    const int fr = lane & 15;
    const int ksw = ((lane >> 4) ^ (lane & 3)) * 8;
    int aoff[2], boff[4];
#pragma unroll
    for (int mi = 0; mi < 2; ++mi) aoff[mi] = (wr + mi * 16 + fr) * 32 + ksw;
#pragma unroll
    for (int ni = 0; ni < 4; ++ni) boff[ni] = (wc + ni * 16 + fr) * 32 + ksw;

    f32x4 acc[2][4];
#pragma unroll
    for (int mi = 0; mi < 2; ++mi)
#pragma unroll
        for (int ni = 0; ni < 4; ++ni) acc[mi][ni] = (f32x4){0.f, 0.f, 0.f, 0.f};

    STAGE(0, 0);
    __syncthreads();
    int cur = 0;
    for (int k0 = 0; k0 < g.Kc; k0 += 32) {
        if (k0 + 32 < g.Kc) STAGE(cur ^ 1, k0 + 32);   // prefetch next K-tile

        half8 fa[2], fb[4];
#pragma unroll
        for (int mi = 0; mi < 2; ++mi) fa[mi] = *(half8*)&LA[cur * 2048 + aoff[mi]];
#pragma unroll
        for (int ni = 0; ni < 4; ++ni) fb[ni] = *(half8*)&LW[cur * 4096 + boff[ni]];
#pragma unroll
        for (int mi = 0; mi < 2; ++mi)
#pragma unroll
            for (int ni = 0; ni < 4; ++ni)
                acc[mi][ni] = __builtin_amdgcn_mfma_f32_16x16x32_f16(fa[mi], fb[ni], acc[mi][ni], 0, 0, 0);
        __syncthreads();
        cur ^= 1;
    }

    const int q4 = (lane >> 4) * 4;
    float gg = 0.f;
    if constexpr (EPI == EPI_FINAL) gg = g.gamma[0];
#pragma unroll
    for (int mi = 0; mi < 2; ++mi)
#pragma unroll
        for (int ni = 0; ni < 4; ++ni)
#pragma unroll
            for (int qi = 0; qi < 4; ++qi) {
                int m = row0 + wr + mi * 16 + q4 + qi;
                int n = col0 + wc + ni * 16 + fr;
                if (m >= g.M || n >= g.N) continue;
                float v = acc[mi][ni][qi];
                if (g.bias) v += g.bias[bz * g.sB + n];
                if constexpr (EPI == EPI_PART) {
                    g.fO[(long)bzf * g.sC + (long)m * g.ldc + n] = v;
                } else if constexpr (EPI == EPI_F16) {
                    g.bO[(long)bzf * g.sC + (long)m * g.ldc + n] = f2h(v);
                } else if constexpr (EPI == EPI_QK2) {
                    // n<128: K channel 128+n scatter into Km ; n>=128: Q col n
                    ushort h = f2h(v);
                    if (n < 128) {
                        int c = 128 + n;
                        int p = m % 49, img = m / 49, f = img & 7, b = img >> 3;
                        int flat = (p / 7) * 14336 + f * 1792 + (p % 7) * 256 + c;
                        int ci = flat / 392, mm = flat % 392;
                        g.bO2[(long)b * 100352 + (long)mm * 256 + ci] = h;
                    } else {
                        g.bO[m * 256 + n] = h;
                    }
                } else {
                    int nimg = m / 49, p = m % 49;
                    long xi = (long)nimg * (2048 * 49) + (long)n * 49 + p;
                    float xv = g.ex[xi];
                    g.fout[xi] = (gg * v + xv) * v + xv;
                }
            }
}

template<int EPI>
__global__ __launch_bounds__(256)
void gmm(GA g)
{
    __shared__ __align__(16) ushort LA[2 * 2048], LW[2 * 4096];
    gmm_body<EPI>(g, blockIdx.x, blockIdx.y, blockIdx.z, LA, LW);
}

// Flat-grid final GEMM with XCD swizzle: 400 blocks = 8 x 50 (bijective).
__global__ __launch_bounds__(256)
void gmmF(GA g)
{
    __shared__ __align__(16) ushort LA[2 * 2048], LW[2 * 4096];
    int id = blockIdx.x;
    id = (id & 7) * 50 + (id >> 3);                // XCD-chunked remap
    gmm_body<EPI_FINAL>(g, id % g.nx, id / g.nx, 0, LA, LW);
}

// Flat-grid quad GEMM with XCD swizzle: [0,n1) g1 ; [n1,+n2) g2 ; [..,+n3) g3 ;
// rest g4. Grid must be 792 = 8 x 99 (bijective remap).
__global__ __launch_bounds__(256)
void gmm4(GA g1, int n1, GA g2, int n2, GA g3, int n3, GA g4)
{
    __shared__ __align__(16) ushort LA[2 * 2048], LW[2 * 4096];
    int id = blockIdx.x;
    id = (id & 7) * 99 + (id >> 3);                // XCD-chunked remap
    if (id < n1) {
        int bx = id % g1.nx, t = id / g1.nx;
        gmm_body<EPI_PART>(g1, bx, t % g1.ny, t / g1.ny, LA, LW);
    } else if (id < n1 + n2) {
        id -= n1;
        int bx = id % g2.nx, t = id / g2.nx;
        gmm_body<EPI_PART>(g2, bx, t % g2.ny, t / g2.ny, LA, LW);
    } else if (id < n1 + n2 + n3) {
        id -= n1 + n2;
        int bx = id % g3.nx, t = id / g3.nx;
        gmm_body<EPI_PART>(g3, bx, t % g3.ny, t / g3.ny, LA, LW);
    } else {
        id -= n1 + n2 + n3;
        int bx = id % g4.nx, t = id / g4.nx;
        gmm_body<EPI_PART>(g4, bx, t % g4.ny, t / g4.ny, LA, LW);
    }
}

// prep: [0,12290) weight conversions ; [12290,14338) activation transposes ;
// [14338,14722) weight transposes (w2u, w2uY, wv). All f16 single plane.
__global__ __launch_bounds__(256)
void prep(const float* c11, const float* c21, const float* conv3,
          const float* c22, const float* c12, const float* wval,
          const float* w2dX, const float* w2dY,
          const float* b_c11, const float* b_c21, const float* b_conv3,
          const float* x, const float* dX,
          const float* w2u, const float* w2uY, const float* wv,
          ushort* Wg1, ushort* C2, ushort* Wval, ushort* W2dS, float* bg1,
          ushort* Xt, ushort* DXt,
          ushort* W2uT, ushort* WvT)
{
    __shared__ float tile[64][65];
    int b = blockIdx.x;
    int tid = threadIdx.x;
    if (b < 12290) {
        int e = b * 256 + tid;
        if (e < 1048576) {
            float v = e < 262144 ? c11[e] : e < 524288 ? c21[e - 262144] : conv3[e - 524288];
            Wg1[e] = f2h(v);
        } else if (e < 1572864) {
            int i = e - 1048576;
            C2[i] = f2h(i < 262144 ? c22[i] : c12[i - 262144]);
        } else if (e < 2097152) {
            int i = e - 1572864; Wval[i] = f2h(wval[i]);
        } else if (e < 2097664) {
            int i = e - 2097152;
            bg1[i] = i < 128 ? b_c11[i] : i < 256 ? b_c21[i - 128] : b_conv3[i - 256];
        } else {
            int i = e - 2097664;                   // < 1048576
            W2dS[i] = f2h(i < 524288 ? w2dX[i] : w2dY[i - 524288]);
        }
    } else if (b < 14338) {
        int local = b - 12290;                 // 0..2047
        int z = local >> 10;
        int rem = local & 1023;
        int n = rem & 31, c0 = (rem >> 5) * 64;
        const float* src = z ? dX : x;
        ushort* oh = z ? DXt : Xt;
        const float* s = src + (long)n * (2048 * 49) + (long)c0 * 49;
        for (int idx = tid; idx < 64 * 49; idx += 256)
            tile[idx / 49][idx % 49] = s[idx];
        __syncthreads();
        for (int idx = tid; idx < 49 * 64; idx += 256) {
            int p = idx >> 6, cl = idx & 63;
            long o = (long)(n * 49 + p) * 2048 + c0 + cl;
            oh[o] = f2h(tile[cl][p]);
        }
    } else {
        int local = b - 14338;                // 0..383
        int zc = local >> 7, t = local & 127;
        const float* src; ushort* dh;
        switch (zc) {
            case 0:  src = w2u;  dh = W2uT;          break;
            case 1:  src = w2uY; dh = W2uT + 524288; break;
            default: src = wv;   dh = WvT;           break;
        }
        const int rows = 2048, cols = 256;
        int tilesX = cols >> 6;               // 4
        int tx = t % tilesX, ty = t / tilesX;
        for (int i = tid; i < 4096; i += 256) {
            int r = i >> 6, c = i & 63;
            tile[r][c] = src[(long)(ty * 64 + r) * cols + tx * 64 + c];
        }
        __syncthreads();
        for (int i = tid; i < 4096; i += 256) {
            int c = i >> 6, r = i & 63;
            long o = (long)(tx * 64 + c) * rows + ty * 64 + r;
            dh[o] = f2h(tile[r][c]);
        }
    }
}

// Fused reduces: [0,3136) r_g1 (4 chunks) ; [3136,3200) A1 reduce ;
// [3200,3232) D reduce -> DT ; [3232,3360) dvec ; [3360,4928) P0 reduce (4 chunks).
__global__ __launch_bounds__(256)
void redA(const float* __restrict__ PG1, const float* __restrict__ bg1,
          const float* __restrict__ pos,
          ushort* Q, ushort* Km, ushort* V,
          const float* __restrict__ A1p, ushort* A1,
          const float* __restrict__ Dp, ushort* DT,
          const float* __restrict__ P0p, ushort* P0,
          const float* w2dX, const float* w2dY,
          const float* b1dX, const float* b1uX, const float* b2dX,
          const float* b1dY, const float* b1uY, const float* b2dY,
          float* __restrict__ dvec)
{
    int blk = blockIdx.x, tid = threadIdx.x;
    if (blk < 3136) {
        int idx = blk * 256 + tid;                 // 1568*512
        int m = idx >> 9, n = idx & 511;
        float v = bg1[n];
#pragma unroll
        for (int k = 0; k < 4; ++k) v += PG1[(long)k * 802816 + idx];
        int p = m % 49, img = m / 49;
        int f = img & 7, b = img >> 3;
        if (n < 128) {
            Q[m * 256 + n] = f2h(v);
        } else if (n < 256) {
            int c = n - 128;
            int flat = (p / 7) * 14336 + f * 1792 + (p % 7) * 256 + c;
            int ci = flat / 392, mm = flat % 392;
            Km[(long)b * 100352 + (long)mm * 256 + ci] = f2h(v);
        } else {
            int c = n - 256;
            v += pos[f * 12544 + c * 49 + p];
            int s = m % 392;
            long o = (long)b * 106496 + (long)c * 416 + s;
            V[o] = f2h(v);
            if (s < 24) V[o + 392] = 0;            // zero K-pad columns
        }
    } else if (blk < 3200) {
        int b2 = blk - 3136;                       // 0..63
#pragma unroll
        for (int r = 0; r < 4; ++r) {
            int idx = b2 * 1024 + r * 256 + tid;   // < 65536
            int z = idx >> 15, e = idx & 32767;
            float v = 0.f;
#pragma unroll
            for (int k = 0; k < 8; ++k) v += A1p[(long)(z * 8 + k) * 32768 + e];
            A1[idx] = f2h(v);
        }
    } else if (blk < 3232) {
        int b2 = blk - 3200;                       // 0..31
#pragma unroll
        for (int r = 0; r < 16; ++r) {
            int idx = b2 * 4096 + r * 256 + tid;   // < 131072
            int z = idx >> 16, e = idx & 65535;
            int i = e >> 8, j = e & 255;
            float v = 0.f;
#pragma unroll
            for (int k = 0; k < 8; ++k) v += Dp[(long)(z * 8 + k) * 65536 + e];
            DT[(long)z * 65536 + (long)j * 256 + i] = f2h(v);   // DT = D^T
        }
    } else if (blk < 3360) {
        int blk2 = blk - 3232;                     // 0..127
        int z = blk2 >> 6;
        int lane = tid & 63, wv = tid >> 6;
        int c = (blk2 & 63) * 4 + wv;
        const float* w2d = (z ? w2dY : w2dX) + (long)c * 2048;
        const float* b1d = z ? b1dY : b1dX;
        const float* b1u = z ? b1uY : b1uX;
        const float* b2d = z ? b2dY : b2dX;
        float acc = 0.f;
        for (int o = lane; o < 2048; o += 64) acc = fmaf(w2d[o], b1u[o], acc);
        for (int j = lane; j < 256; j += 64) {
            float d = 0.f;
#pragma unroll
            for (int k = 0; k < 8; ++k) d += Dp[(long)(z * 8 + k) * 65536 + (long)c * 256 + j];
            acc = fmaf(d, b1d[j], acc);
        }
        for (int off = 32; off; off >>= 1) acc += __shfl_down(acc, off, 64);
        if (lane == 0) dvec[z * 256 + c] = acc + b2d[c];
    } else {
        int idx = (blk - 3360) * 256 + tid;        // < 401408
        float v = 0.f;
#pragma unroll
        for (int k = 0; k < 4; ++k) v += P0p[(long)k * 401408 + idx];
        P0[idx] = f2h(v);
    }
}

// A3+kc launch: [0,8) gmm (A3 = A1 @ DT^T, f16) ; [8,72) kc (wave/output):
//   kc_z[i] = A1_z[i]·dvec_z + C2_z[i]·b2u_z + bc_z[i]
__global__ __launch_bounds__(256)
void a3kc(GA gA3,
          const ushort* __restrict__ A1, const float* __restrict__ dvec,
          const float* c22, const float* c12,
          const float* b2uX, const float* b2uY,
          const float* bc22, const float* bc12, float* kc)
{
    __shared__ __align__(16) ushort LA[2 * 2048], LW[2 * 4096];
    int id = blockIdx.x;
    if (id < 8) {
        int bx = id & 1, t = id >> 1;
        gmm_body<EPI_F16>(gA3, bx, t & 1, t >> 1, LA, LW);
        return;
    }
    int tid = threadIdx.x, lane = tid & 63, wv = tid >> 6;
    int w = (id - 8) * 4 + wv;                     // 0..255
    int z = w >> 7, i = w & 127;
    const ushort* a1 = A1 + (long)z * 32768 + i * 256;
    const float* dv = dvec + z * 256;
    const float* cr = (z ? c12 : c22) + (long)i * 2048;
    const float* b2u = z ? b2uY : b2uX;
    float acc = 0.f;
    for (int c = lane; c < 256; c += 64) acc = fmaf(h2f(a1[c]), dv[c], acc);
    for (int o = lane; o < 2048; o += 64) acc = fmaf(cr[o], b2u[o], acc);
    for (int off = 32; off; off >>= 1) acc += __shfl_down(acc, off, 64);
    if (lane == 0) kc[z * 128 + i] = acc + (z ? bc12 : bc22)[i];
}

// Fused attention, 512 threads / 8 waves: waves split the 26 col-frags by 8
// (phase 1) and the 16 PV channel-frags by 2 (phase 3). Softmax (phase 2)
// runs on threads 0..255. Block = 16 Q-rows x one batch, grid 25x4.
__global__ __launch_bounds__(512)
void fattn(const ushort* __restrict__ Qg, const ushort* __restrict__ Kmg,
           const ushort* __restrict__ VT, ushort* __restrict__ O)
{
    __shared__ float raw[16 * 420];
    __shared__ ushort P[16 * 424];
    const int b = blockIdx.y;
    const int r0 = blockIdx.x * 16;
    const int tid = threadIdx.x;
    const int lane = tid & 63, wv = tid >> 6;      // 8 waves
    const int fr = lane & 15, g = lane >> 4;
    const int kb = g * 8;
    const long base = (long)b * 100352;
    const long vbase = (long)b * 106496;

    int qr = r0 + fr; if (qr > 391) qr = 391;
    const ushort* qp = Qg + base + (long)qr * 256 + kb;
    half8 qh[8];
#pragma unroll
    for (int kf = 0; kf < 8; ++kf) qh[kf] = *(const half8*)(qp + kf * 32);

    // Phase 1: wave wv handles nf = wv, wv+8, ... (26 col-frags of 16)
    for (int nf = wv; nf < 26; nf += 8) {
        int kcol = nf * 16 + fr; if (kcol > 391) kcol = 391;
        const ushort* kp = Kmg + base + (long)kcol * 256 + kb;
        f32x4 a = (f32x4){0.f, 0.f, 0.f, 0.f};
#pragma unroll
        for (int kf = 0; kf < 8; ++kf) {
            half8 bh = *(const half8*)(kp + kf * 32);
            a = __builtin_amdgcn_mfma_f32_16x16x32_f16(qh[kf], bh, a, 0, 0, 0);
        }
#pragma unroll
        for (int q = 0; q < 4; ++q)
            raw[(g * 4 + q) * 420 + nf * 16 + fr] = a[q];
    }
    __syncthreads();

    // Phase 2: softmax on threads 0..255 (row = tid>>4, j = tid&15)
    if (tid < 256) {
        int row = tid >> 4, j = tid & 15;
        float v[26];
        float m = -1e30f;
#pragma unroll
        for (int k = 0; k < 26; ++k) {
            int col = j + 16 * k;
            v[k] = (col < 392) ? raw[row * 420 + col] : -1e30f;
            m = fmaxf(m, v[k]);
        }
#pragma unroll
        for (int off = 8; off; off >>= 1) m = fmaxf(m, __shfl_xor(m, off, 16));
        float s = 0.f;
#pragma unroll
        for (int k = 0; k < 26; ++k) { v[k] = __expf(v[k] - m); s += v[k]; }
#pragma unroll
        for (int off = 8; off; off >>= 1) s += __shfl_xor(s, off, 16);
        float inv = 1.f / s;
#pragma unroll
        for (int k = 0; k < 26; ++k) {
            int col = j + 16 * k;
            P[row * 424 + col] = (col < 392) ? f2h(v[k] * inv) : (ushort)0;
        }
    }
    __syncthreads();

    // Phase 3: PV. wave wv computes output channel frags wv*2, wv*2+1.
    const int cf0 = wv * 2;
    f32x4 o[2];
#pragma unroll
    for (int c = 0; c < 2; ++c) o[c] = (f32x4){0.f, 0.f, 0.f, 0.f};
#pragma unroll
    for (int kf = 0; kf < 13; ++kf) {
        half8 pa = *(half8*)&P[fr * 424 + kf * 32 + kb];
#pragma unroll
        for (int c = 0; c < 2; ++c) {
            const ushort* vp = VT + vbase + (long)((cf0 + c) * 16 + fr) * 416 + kf * 32 + kb;
            half8 vb = *(const half8*)vp;
            o[c] = __builtin_amdgcn_mfma_f32_16x16x32_f16(pa, vb, o[c], 0, 0, 0);
        }
    }
#pragma unroll
    for (int c = 0; c < 2; ++c)
#pragma unroll
        for (int q = 0; q < 4; ++q) {
            int orow = r0 + g * 4 + q;
            if (orow < 392)
                O[base + (long)orow * 256 + (cf0 + c) * 16 + fr] = f2h(o[c][q]);
        }
}

extern "C" void kernel_launch(void* const* d_in, const int* in_sizes, int n_in,
                              void* d_out, int out_size, void* d_ws, size_t ws_size,
                              hipStream_t stream)
{
    const float* x        = (const float*)d_in[0];
    const float* domainX  = (const float*)d_in[1];
    const float* w_conv3  = (const float*)d_in[5];
    const float* b_conv3  = (const float*)d_in[6];
    const float* w_value  = (const float*)d_in[7];
    const float* b_value  = (const float*)d_in[8];
    const float* b_l1down   = (const float*)d_in[9];
    const float* b_l1up     = (const float*)d_in[10];
    const float* b_l1down_Y = (const float*)d_in[11];
    const float* b_l1up_Y   = (const float*)d_in[12];
    const float* w_l2down   = (const float*)d_in[13];
    const float* b_l2down   = (const float*)d_in[14];
    const float* w_l2up     = (const float*)d_in[15];
    const float* b_l2up     = (const float*)d_in[16];
    const float* w_l2down_Y = (const float*)d_in[17];
    const float* b_l2down_Y = (const float*)d_in[18];
    const float* w_l2up_Y   = (const float*)d_in[19];
    const float* b_l2up_Y   = (const float*)d_in[20];
    const float* w_c11 = (const float*)d_in[21];
    const float* b_c11 = (const float*)d_in[22];
    const float* w_c12 = (const float*)d_in[23];
    const float* b_c12 = (const float*)d_in[24];
    const float* w_c21 = (const float*)d_in[25];
    const float* b_c21 = (const float*)d_in[26];
    const float* w_c22 = (const float*)d_in[27];
    const float* b_c22 = (const float*)d_in[28];
    const float* pos   = (const float*)d_in[29];
    const float* gamma = (const float*)d_in[30];
    float* out = (float*)d_out;

    ushort* U = (ushort*)d_ws;
    float*  Fp = (float*)d_ws;

    // ---- flat workspace (ushort elems; f32 region after) ----
    const long oXt   = 0;            // [1568][2048]
    const long oDXt  = 3211264;
    const long oWg1  = 6422528;      // [512][2048] c11|c21|conv3
    const long oWval = 7471104;      // [2048][256]
    const long oC2   = 7995392;      // [2][128][2048]
    const long oW2uT = 8519680;      // [2][256][2048]
    const long oWvT  = 9568256;      // [256][2048]
    const long oW2dS = 10092544;     // [2][256][2048]
    const long oQ    = 11141120;     // [1568][256]
    const long oKm   = 11542528;     // [4][392][256]
    const long oVT   = 11943936;     // [4][256][416]
    const long oA1   = 12369920;     // [2][128][256]
    const long oDT   = 12435456;     // [2][256][256]
    const long oA3   = 12566528;     // [2][128][256] = flat [256][256]
    const long oP0   = 12632064;     // [1568][256]
    const long oO    = 13033472;     // [1568][256], ends 13,434,880
    // float offsets (float elems)
    const long fPG1  = 6979584;      // [4][1568][512]
    const long fP0p  = 13402112;     // [4][1568][256]
    const long fA1p  = 15007744;     // [16][128][256]
    const long fDp   = 15532032;     // [16][256][256]
    const long fbg1  = 16580608;     // 512
    const long fkc   = 16581120;     // 256
    const long fdv   = 16581376;     // 512

    GA Z = {};

    // 1. prep
    prep<<<dim3(14722), 256, 0, stream>>>(
        w_c11, w_c21, w_conv3, w_c22, w_c12, w_value, w_l2down, w_l2down_Y,
        b_c11, b_c21, b_conv3, x, domainX,
        w_l2up, w_l2up_Y, w_value,
        U + oWg1, U + oC2, U + oWval, U + oW2dS, Fp + fbg1,
        U + oXt, U + oDXt,
        U + oW2uT, U + oWvT);

    // 2. G1 (400, split-K 4) + A1 partials (64) + D partials (128) + P0 partials (200)
    {
        GA g1 = Z;
        g1.Ah = U + oXt; g1.lda = 2048; g1.sA = 0;
        g1.Wh = U + oWg1; g1.ldw = 2048; g1.sW = 0;
        g1.nkc = 4; g1.Kc = 512; g1.fO = Fp + fPG1;
        g1.ldc = 512; g1.sC = 802816; g1.M = TOKENS; g1.N = 512; g1.nx = 4; g1.ny = 25;
        GA ga1 = Z;
        ga1.Ah = U + oC2; ga1.lda = 2048; ga1.sA = 262144;
        ga1.Wh = U + oW2uT; ga1.ldw = 2048; ga1.sW = 524288;
        ga1.nkc = 8; ga1.Kc = 256; ga1.fO = Fp + fA1p;
        ga1.ldc = 256; ga1.sC = 32768; ga1.M = 128; ga1.N = 256; ga1.nx = 2; ga1.ny = 2;
        GA gd = Z;
        gd.Ah = U + oW2dS; gd.lda = 2048; gd.sA = 524288;
        gd.Wh = U + oWvT; gd.ldw = 2048; gd.sW = 0;
        gd.nkc = 8; gd.Kc = 256; gd.fO = Fp + fDp;
        gd.ldc = 256; gd.sC = 65536; gd.M = 256; gd.N = 256; gd.nx = 2; gd.ny = 4;
        GA gp = Z;
        gp.Ah = U + oDXt; gp.lda = 2048; gp.sA = 0;
        gp.Wh = U + oWg1 + 524288; gp.ldw = 2048; gp.sW = 0;   // conv3 rows
        gp.nkc = 4; gp.Kc = 512; gp.fO = Fp + fP0p;
        gp.ldc = 256; gp.sC = 401408; gp.M = TOKENS; gp.N = 256; gp.nx = 2; gp.ny = 25;
        gmm4<<<dim3(792), 256, 0, stream>>>(g1, 400, ga1, 64, gd, 128, gp);
    }

    // 3. r_g1 (4 chunks) + A1 reduce + D reduce->DT + dvec + P0 reduce
    redA<<<dim3(4928), 256, 0, stream>>>(Fp + fPG1, Fp + fbg1, pos,
        U + oQ, U + oKm, U + oVT,
        Fp + fA1p, U + oA1,
        Fp + fDp, U + oDT,
        Fp + fP0p, U + oP0,
        w_l2down, w_l2down_Y,
        b_l1down, b_l1up, b_l2down,
        b_l1down_Y, b_l1up_Y, b_l2down_Y,
        Fp + fdv);

    // 4. A3 = A1 @ DT^T (8 blocks, f16) + kc (64 wave-parallel blocks)
    {
        GA g = Z;
        g.Ah = U + oA1; g.lda = 256; g.sA = 32768;
        g.Wh = U + oDT; g.ldw = 256; g.sW = 65536;
        g.nkc = 1; g.Kc = 256; g.bO = U + oA3;
        g.ldc = 256; g.sC = 32768; g.M = 128; g.N = 256; g.nx = 2; g.ny = 2;
        a3kc<<<dim3(72), 256, 0, stream>>>(g,
            U + oA1, Fp + fdv,
            w_c22, w_c12, b_l2up, b_l2up_Y,
            b_c22, b_c12, Fp + fkc);
    }

    // 5. GQK2 = P0 @ A3^T + kc, fused Q/Km scatter epilogue (K=256, 50 blocks)
    {
        GA g = Z;
        g.Ah = U + oP0; g.lda = 256; g.sA = 0;
        g.Wh = U + oA3; g.ldw = 256; g.sW = 0;
        g.bias = Fp + fkc; g.sB = 0;
        g.nkc = 1; g.Kc = 256;
        g.bO = U + oQ; g.bO2 = U + oKm;
        g.ldc = 0; g.sC = 0; g.M = TOKENS; g.N = 256; g.nx = 2; g.ny = 25;
        gmm<EPI_QK2><<<dim3(2, 25, 1), 256, 0, stream>>>(g);
    }

    // 6. fused attention (100 blocks x 8 waves)
    fattn<<<dim3(25, 4), 512, 0, stream>>>(U + oQ, U + oKm, U + oVT, U + oO);

    // 7. final: z = O @ w_value^T + b_value ; out = (g*z + x)*z + x  (XCD swizzle)
    {
        GA g = Z;
        g.Ah = U + oO; g.lda = 256; g.sA = 0;
        g.Wh = U + oWval; g.ldw = 256; g.sW = 0;
        g.bias = b_value; g.sB = 0;
        g.nkc = 1; g.Kc = 256;
        g.ldc = 0; g.sC = 0; g.M = TOKENS; g.N = 2048; g.nx = 16; g.ny = 25;
        g.ex = x; g.gamma = gamma; g.fout = out;
        gmmF<<<dim3(400), 256, 0, stream>>>(g);
    }
}